// Round 1
// baseline (8940.576 us; speedup 1.0000x reference)
//
#include <hip/hip_runtime.h>
#include <math.h>

namespace {

constexpr int Bn = 256;
constexpr int Tn = 128;
constexpr int Dn = 256;
constexpr int Hn = 512;
constexpr int BT = Bn * Tn;

__device__ __forceinline__ float sigm(float v) { return 1.0f / (1.0f + expf(-v)); }

// h_hist[0][b][h] = h0[h]; c_buf[0][b][h] = c0[h]
__global__ __launch_bounds__(256) void k_init(const float* __restrict__ h0,
                                              const float* __restrict__ c0,
                                              float* __restrict__ h_hist,
                                              float* __restrict__ c_buf) {
  int i = blockIdx.x * 256 + threadIdx.x;  // [0, Bn*Hn)
  int h = i & (Hn - 1);
  h_hist[i] = h0[h];
  c_buf[i] = c0[h];
}

// gamma_h[m,n] = exp(-relu(dt[m,:]@w_gh[:,n] + h_gh[n]))  (M=BT, K=Dn, N=Hn)
__global__ __launch_bounds__(256) void k_gamma_h(const float* __restrict__ dt,
                                                 const float* __restrict__ w,
                                                 const float* __restrict__ bias,
                                                 float* __restrict__ outg) {
  __shared__ float As[64][17];
  __shared__ float Bs[16][64];
  int tid = threadIdx.x;
  int tx = tid & 15, ty = tid >> 4;
  int m0 = blockIdx.y * 64, n0 = blockIdx.x * 64;
  float acc[4][4] = {};
  for (int k0 = 0; k0 < Dn; k0 += 16) {
    {
      int ml = tid >> 2, kk = (tid & 3) * 4;
      float4 v = *(const float4*)(dt + (size_t)(m0 + ml) * Dn + k0 + kk);
      As[ml][kk + 0] = v.x; As[ml][kk + 1] = v.y;
      As[ml][kk + 2] = v.z; As[ml][kk + 3] = v.w;
    }
    {
      int kb = (tid >> 6) * 4, nl = tid & 63;
#pragma unroll
      for (int r = 0; r < 4; ++r)
        Bs[kb + r][nl] = w[(size_t)(k0 + kb + r) * Hn + n0 + nl];
    }
    __syncthreads();
#pragma unroll
    for (int kk = 0; kk < 16; ++kk) {
      float a[4], b[4];
#pragma unroll
      for (int i = 0; i < 4; ++i) a[i] = As[ty + 16 * i][kk];
#pragma unroll
      for (int j = 0; j < 4; ++j) b[j] = Bs[kk][tx + 16 * j];
#pragma unroll
      for (int i = 0; i < 4; ++i)
#pragma unroll
        for (int j = 0; j < 4; ++j) acc[i][j] += a[i] * b[j];
    }
    __syncthreads();
  }
#pragma unroll
  for (int j = 0; j < 4; ++j) {
    int n = n0 + tx + 16 * j;
    float bv = bias[n];
#pragma unroll
    for (int i = 0; i < 4; ++i) {
      int m = m0 + ty + 16 * i;
      float v = acc[i][j] + bv;
      outg[(size_t)m * Hn + n] = expf(-fmaxf(v, 0.0f));
    }
  }
}

// gamma_x GEMM (N=Dn) fused with imputation; writes xs into out xhats [T,B,D]
__global__ __launch_bounds__(256) void k_xs(const float* __restrict__ dt,
                                            const float* __restrict__ w,
                                            const float* __restrict__ bias,
                                            const float* __restrict__ x,
                                            const float* __restrict__ mask,
                                            const float* __restrict__ xmean,
                                            float* __restrict__ out_xs) {
  __shared__ float As[64][17];
  __shared__ float Bs[16][64];
  int tid = threadIdx.x;
  int tx = tid & 15, ty = tid >> 4;
  int m0 = blockIdx.y * 64, n0 = blockIdx.x * 64;
  float acc[4][4] = {};
  for (int k0 = 0; k0 < Dn; k0 += 16) {
    {
      int ml = tid >> 2, kk = (tid & 3) * 4;
      float4 v = *(const float4*)(dt + (size_t)(m0 + ml) * Dn + k0 + kk);
      As[ml][kk + 0] = v.x; As[ml][kk + 1] = v.y;
      As[ml][kk + 2] = v.z; As[ml][kk + 3] = v.w;
    }
    {
      int kb = (tid >> 6) * 4, nl = tid & 63;
#pragma unroll
      for (int r = 0; r < 4; ++r)
        Bs[kb + r][nl] = w[(size_t)(k0 + kb + r) * Dn + n0 + nl];
    }
    __syncthreads();
#pragma unroll
    for (int kk = 0; kk < 16; ++kk) {
      float a[4], b[4];
#pragma unroll
      for (int i = 0; i < 4; ++i) a[i] = As[ty + 16 * i][kk];
#pragma unroll
      for (int j = 0; j < 4; ++j) b[j] = Bs[kk][tx + 16 * j];
#pragma unroll
      for (int i = 0; i < 4; ++i)
#pragma unroll
        for (int j = 0; j < 4; ++j) acc[i][j] += a[i] * b[j];
    }
    __syncthreads();
  }
#pragma unroll
  for (int j = 0; j < 4; ++j) {
    int d = n0 + tx + 16 * j;
    float bv = bias[d];
    float xm = xmean[d];
#pragma unroll
    for (int i = 0; i < 4; ++i) {
      int m = m0 + ty + 16 * i;
      int b = m >> 7;       // /Tn
      int tt = m & (Tn - 1);
      float g = expf(-fmaxf(acc[i][j] + bv, 0.0f));
      float imput = (tt == 0) ? xm
                              : g * x[(size_t)(m - 1) * Dn + d] + (1.0f - g) * xm;
      float xv = x[(size_t)m * Dn + d];
      float mv = mask[(size_t)m * Dn + d];
      float xsv = xv * mv + (1.0f - mv) * imput;
      out_xs[((size_t)tt * Bn + b) * Dn + d] = xsv;
    }
  }
}

// One recurrent step: gates GEMM ([B,768]@[768,2048 via 4 gates x h-chunk]) + cell
__global__ __launch_bounds__(256) void k_step(int t,
    const float* __restrict__ xs,      // [T,B,D]
    const float* __restrict__ gammaH,  // [BT,H], row = b*Tn + t
    const float* __restrict__ h_prev,  // [B,H]
    float* __restrict__ h_next,        // [B,H]
    const float* __restrict__ c_in,
    float* __restrict__ c_out,
    const float* __restrict__ W_ih,    // [4H, D]
    const float* __restrict__ W_hh,    // [4H, H]
    const float* __restrict__ b_ih,
    const float* __restrict__ b_hh,
    const float* __restrict__ tp,      // [B,T]
    const float* __restrict__ w_t,     // [H]
    const float* __restrict__ h_t) {   // [H]
  __shared__ float As[64][17];
  __shared__ float Bs[64][17];
  int tid = threadIdx.x;
  int tx = tid & 15, ty = tid >> 4;
  int hbase = blockIdx.x * 16;
  int b0 = blockIdx.y * 64;
  float acc[4][4] = {};  // [b micro][gate]
  const float* xs_t = xs + (size_t)t * Bn * Dn;
  for (int k0 = 0; k0 < Dn + Hn; k0 += 16) {
    {  // A tile: 64 b-rows x 16 k; decayed h for k >= Dn
      int bl = tid >> 2, kk = (tid & 3) * 4;
      int b = b0 + bl;
      float4 v;
      if (k0 < Dn) {
        v = *(const float4*)(xs_t + (size_t)b * Dn + k0 + kk);
      } else {
        int kh = k0 - Dn + kk;
        float4 hv = *(const float4*)(h_prev + (size_t)b * Hn + kh);
        float4 gv = *(const float4*)(gammaH + ((size_t)b * Tn + t) * Hn + kh);
        v = make_float4(hv.x * gv.x, hv.y * gv.y, hv.z * gv.z, hv.w * gv.w);
      }
      As[bl][kk + 0] = v.x; As[bl][kk + 1] = v.y;
      As[bl][kk + 2] = v.z; As[bl][kk + 3] = v.w;
    }
    {  // B tile: 64 j-rows x 16 k; j = gate*Hn + hbase + hl
      int r = tid >> 2, kk = (tid & 3) * 4;
      int j = (r >> 4) * Hn + hbase + (r & 15);
      float4 v;
      if (k0 < Dn) v = *(const float4*)(W_ih + (size_t)j * Dn + k0 + kk);
      else         v = *(const float4*)(W_hh + (size_t)j * Hn + (k0 - Dn) + kk);
      Bs[r][kk + 0] = v.x; Bs[r][kk + 1] = v.y;
      Bs[r][kk + 2] = v.z; Bs[r][kk + 3] = v.w;
    }
    __syncthreads();
#pragma unroll
    for (int kk = 0; kk < 16; ++kk) {
      float a[4], b[4];
#pragma unroll
      for (int i = 0; i < 4; ++i) a[i] = As[ty + 16 * i][kk];
#pragma unroll
      for (int g = 0; g < 4; ++g) b[g] = Bs[g * 16 + tx][kk];
#pragma unroll
      for (int i = 0; i < 4; ++i)
#pragma unroll
        for (int g = 0; g < 4; ++g) acc[i][g] += a[i] * b[g];
    }
    __syncthreads();
  }
  int hh = hbase + tx;
  float bi = b_ih[hh] + b_hh[hh];
  float bf = b_ih[Hn + hh] + b_hh[Hn + hh];
  float bg = b_ih[2 * Hn + hh] + b_hh[2 * Hn + hh];
  float bo = b_ih[3 * Hn + hh] + b_hh[3 * Hn + hh];
  float wtv = w_t[hh], htv = h_t[hh];
#pragma unroll
  for (int i = 0; i < 4; ++i) {
    int b = b0 + ty + 16 * i;
    float ig = sigm(acc[i][0] + bi);
    float fg = sigm(acc[i][1] + bf);
    float gg = tanhf(acc[i][2] + bg);
    float og = sigm(acc[i][3] + bo);
    float gh = gammaH[((size_t)b * Tn + t) * Hn + hh];
    float cold = c_in[(size_t)b * Hn + hh] * gh;
    float c1 = fg * cold + ig * gg;
    float gt = sigm(tp[(size_t)b * Tn + t] * wtv + htv);
    float h1 = gt * og * tanhf(c1);
    c1 *= gt;
    h_next[(size_t)b * Hn + hh] = h1;
    c_out[(size_t)b * Hn + hh] = c1;
  }
}

// Batched output head over all (t,b) rows; h1 read from h_hist[t+1]
__global__ __launch_bounds__(256) void k_head(const float* __restrict__ h_hist,
                                              const float* __restrict__ W1,
                                              const float* __restrict__ b1,
                                              const float* __restrict__ W2,
                                              const float* __restrict__ b2,
                                              float* __restrict__ outs) {
  __shared__ float sW1[Hn * 10];
  for (int i = threadIdx.x; i < Hn * 10; i += 256) sW1[i] = W1[i];
  __syncthreads();
  int idx = blockIdx.x * 256 + threadIdx.x;  // idx = tt*Bn + b
  int tt = idx >> 8;                         // /Bn
  int b = idx & (Bn - 1);
  const float4* row =
      (const float4*)(h_hist + ((size_t)(tt + 1) * Bn + b) * Hn);
  float z1[10];
#pragma unroll
  for (int k = 0; k < 10; ++k) z1[k] = b1[k];
  for (int hq = 0; hq < Hn / 4; ++hq) {
    float4 hv = row[hq];
    float hvv[4] = {hv.x, hv.y, hv.z, hv.w};
    int hb = hq * 4;
#pragma unroll
    for (int c = 0; c < 4; ++c)
#pragma unroll
      for (int k = 0; k < 10; ++k) z1[k] += hvv[c] * sW1[(hb + c) * 10 + k];
  }
#pragma unroll
  for (int k = 0; k < 10; ++k) z1[k] = sigm(z1[k]);
  float z2[2];
#pragma unroll
  for (int c = 0; c < 2; ++c) {
    float v = b2[c];
#pragma unroll
    for (int k = 0; k < 10; ++k) v += z1[k] * W2[k * 2 + c];
    z2[c] = sigm(v);
  }
  float mx = fmaxf(z2[0], z2[1]);
  float e0 = expf(z2[0] - mx), e1 = expf(z2[1] - mx);
  float s = e0 + e1;
  outs[(size_t)idx * 2 + 0] = e0 / s;
  outs[(size_t)idx * 2 + 1] = e1 / s;
}

}  // namespace

extern "C" void kernel_launch(void* const* d_in, const int* in_sizes, int n_in,
                              void* d_out, int out_size, void* d_ws,
                              size_t ws_size, hipStream_t stream) {
  (void)in_sizes; (void)n_in; (void)out_size; (void)ws_size;
  const float* x     = (const float*)d_in[0];
  const float* dt    = (const float*)d_in[1];
  const float* mask  = (const float*)d_in[2];
  const float* tp    = (const float*)d_in[3];
  const float* xmean = (const float*)d_in[4];
  const float* h0    = (const float*)d_in[5];
  const float* c0    = (const float*)d_in[6];
  const float* w_gx  = (const float*)d_in[7];
  const float* h_gx  = (const float*)d_in[8];
  const float* w_gh  = (const float*)d_in[9];
  const float* h_gh  = (const float*)d_in[10];
  const float* w_t   = (const float*)d_in[11];
  const float* h_t   = (const float*)d_in[12];
  const float* W_ih  = (const float*)d_in[13];
  const float* W_hh  = (const float*)d_in[14];
  const float* b_ih  = (const float*)d_in[15];
  const float* b_hh  = (const float*)d_in[16];
  const float* oW1   = (const float*)d_in[17];
  const float* ob1   = (const float*)d_in[18];
  const float* oW2   = (const float*)d_in[19];
  const float* ob2   = (const float*)d_in[20];

  float* out  = (float*)d_out;
  float* outs = out;                        // [T,B,2]
  float* xhat = out + (size_t)Tn * Bn * 2;  // [T,B,D] (= xs; reused as GEMM input)

  float* ws     = (float*)d_ws;
  float* gammaH = ws;                                  // BT*H floats
  float* h_hist = gammaH + (size_t)BT * Hn;            // (T+1)*B*H floats
  float* c_buf  = h_hist + (size_t)(Tn + 1) * Bn * Hn; // 2*B*H floats

  k_init<<<(Bn * Hn) / 256, 256, 0, stream>>>(h0, c0, h_hist, c_buf);
  k_gamma_h<<<dim3(Hn / 64, BT / 64), 256, 0, stream>>>(dt, w_gh, h_gh, gammaH);
  k_xs<<<dim3(Dn / 64, BT / 64), 256, 0, stream>>>(dt, w_gx, h_gx, x, mask,
                                                   xmean, xhat);
  for (int t = 0; t < Tn; ++t) {
    const float* hp = h_hist + (size_t)t * Bn * Hn;
    float* hn       = h_hist + (size_t)(t + 1) * Bn * Hn;
    const float* ci = c_buf + (size_t)(t & 1) * Bn * Hn;
    float* co       = c_buf + (size_t)((t + 1) & 1) * Bn * Hn;
    k_step<<<dim3(Hn / 16, Bn / 64), 256, 0, stream>>>(
        t, xhat, gammaH, hp, hn, ci, co, W_ih, W_hh, b_ih, b_hh, tp, w_t, h_t);
  }
  k_head<<<BT / 256, 256, 0, stream>>>(h_hist, oW1, ob1, oW2, ob2, outs);
}

// Round 2
// 7445.846 us; speedup vs baseline: 1.2007x; 1.2007x over previous
//
#include <hip/hip_runtime.h>
#include <math.h>

namespace {

constexpr int Bn = 256;
constexpr int Tn = 128;
constexpr int Dn = 256;
constexpr int Hn = 512;
constexpr int BT = Bn * Tn;
constexpr int Kt = Dn + Hn;  // 768

constexpr int WS_STRIDE = 772;  // Ws col stride (768 + 4 pad, 16B aligned, banks ok)
constexpr int AS_STRIDE = 68;   // As row stride (64 + 4 pad)
constexpr int GS_STRIDE = 36;   // gate tile stride

__device__ __forceinline__ float sigm(float v) { return 1.0f / (1.0f + expf(-v)); }

// gamma_h[m,n] = exp(-relu(dt[m,:]@w_gh[:,n] + h_gh[n]))  (M=BT, K=Dn, N=Hn)
__global__ __launch_bounds__(256) void k_gamma_h(const float* __restrict__ dt,
                                                 const float* __restrict__ w,
                                                 const float* __restrict__ bias,
                                                 float* __restrict__ outg) {
  __shared__ float As[64][17];
  __shared__ float Bs[16][64];
  int tid = threadIdx.x;
  int tx = tid & 15, ty = tid >> 4;
  int m0 = blockIdx.y * 64, n0 = blockIdx.x * 64;
  float acc[4][4] = {};
  for (int k0 = 0; k0 < Dn; k0 += 16) {
    {
      int ml = tid >> 2, kk = (tid & 3) * 4;
      float4 v = *(const float4*)(dt + (size_t)(m0 + ml) * Dn + k0 + kk);
      As[ml][kk + 0] = v.x; As[ml][kk + 1] = v.y;
      As[ml][kk + 2] = v.z; As[ml][kk + 3] = v.w;
    }
    {
      int kb = (tid >> 6) * 4, nl = tid & 63;
#pragma unroll
      for (int r = 0; r < 4; ++r)
        Bs[kb + r][nl] = w[(size_t)(k0 + kb + r) * Hn + n0 + nl];
    }
    __syncthreads();
#pragma unroll
    for (int kk = 0; kk < 16; ++kk) {
      float a[4], b[4];
#pragma unroll
      for (int i = 0; i < 4; ++i) a[i] = As[ty + 16 * i][kk];
#pragma unroll
      for (int j = 0; j < 4; ++j) b[j] = Bs[kk][tx + 16 * j];
#pragma unroll
      for (int i = 0; i < 4; ++i)
#pragma unroll
        for (int j = 0; j < 4; ++j) acc[i][j] += a[i] * b[j];
    }
    __syncthreads();
  }
#pragma unroll
  for (int j = 0; j < 4; ++j) {
    int n = n0 + tx + 16 * j;
    float bv = bias[n];
#pragma unroll
    for (int i = 0; i < 4; ++i) {
      int m = m0 + ty + 16 * i;
      float v = acc[i][j] + bv;
      outg[(size_t)m * Hn + n] = expf(-fmaxf(v, 0.0f));
    }
  }
}

// gamma_x GEMM (N=Dn) fused with imputation; writes xs into xhats [T,B,D]
__global__ __launch_bounds__(256) void k_xs(const float* __restrict__ dt,
                                            const float* __restrict__ w,
                                            const float* __restrict__ bias,
                                            const float* __restrict__ x,
                                            const float* __restrict__ mask,
                                            const float* __restrict__ xmean,
                                            float* __restrict__ out_xs) {
  __shared__ float As[64][17];
  __shared__ float Bs[16][64];
  int tid = threadIdx.x;
  int tx = tid & 15, ty = tid >> 4;
  int m0 = blockIdx.y * 64, n0 = blockIdx.x * 64;
  float acc[4][4] = {};
  for (int k0 = 0; k0 < Dn; k0 += 16) {
    {
      int ml = tid >> 2, kk = (tid & 3) * 4;
      float4 v = *(const float4*)(dt + (size_t)(m0 + ml) * Dn + k0 + kk);
      As[ml][kk + 0] = v.x; As[ml][kk + 1] = v.y;
      As[ml][kk + 2] = v.z; As[ml][kk + 3] = v.w;
    }
    {
      int kb = (tid >> 6) * 4, nl = tid & 63;
#pragma unroll
      for (int r = 0; r < 4; ++r)
        Bs[kb + r][nl] = w[(size_t)(k0 + kb + r) * Dn + n0 + nl];
    }
    __syncthreads();
#pragma unroll
    for (int kk = 0; kk < 16; ++kk) {
      float a[4], b[4];
#pragma unroll
      for (int i = 0; i < 4; ++i) a[i] = As[ty + 16 * i][kk];
#pragma unroll
      for (int j = 0; j < 4; ++j) b[j] = Bs[kk][tx + 16 * j];
#pragma unroll
      for (int i = 0; i < 4; ++i)
#pragma unroll
        for (int j = 0; j < 4; ++j) acc[i][j] += a[i] * b[j];
    }
    __syncthreads();
  }
#pragma unroll
  for (int j = 0; j < 4; ++j) {
    int d = n0 + tx + 16 * j;
    float bv = bias[d];
    float xm = xmean[d];
#pragma unroll
    for (int i = 0; i < 4; ++i) {
      int m = m0 + ty + 16 * i;
      int b = m >> 7;       // /Tn
      int tt = m & (Tn - 1);
      float g = expf(-fmaxf(acc[i][j] + bv, 0.0f));
      float imput = (tt == 0) ? xm
                              : g * x[(size_t)(m - 1) * Dn + d] + (1.0f - g) * xm;
      float xv = x[(size_t)m * Dn + d];
      float mv = mask[(size_t)m * Dn + d];
      float xsv = xv * mv + (1.0f - mv) * imput;
      out_xs[((size_t)tt * Bn + b) * Dn + d] = xsv;
    }
  }
}

// hdec[0][b][h] = h0[h] * gammaH[b, t=0, h]; zero barrier counters
__global__ __launch_bounds__(256) void k_init(const float* __restrict__ h0,
                                              const float* __restrict__ gammaH,
                                              float* __restrict__ hdec,
                                              int* __restrict__ bar) {
  int i = blockIdx.x * 256 + threadIdx.x;  // [0, Bn*Hn)
  int h = i & (Hn - 1);
  int b = i >> 9;  // /Hn
  hdec[i] = h0[h] * gammaH[((size_t)b * Tn + 0) * Hn + h];
  if (blockIdx.x == 0 && threadIdx.x < 4) bar[threadIdx.x * 128] = 0;
}

// Persistent scan kernel: 256 blocks (1/CU). Block owns 64 batch x (8 h x 4 gates).
// Weights resident in LDS for all 128 steps; c in registers; per-batch-group
// device barrier between steps (4 independent groups of 64 blocks).
__global__ __launch_bounds__(256, 1) void k_scan(
    const float* __restrict__ xs,      // [T,B,D]
    const float* __restrict__ gammaH,  // [(b*Tn+t), H]
    float* __restrict__ hdec,          // [2][B][H] (pre-decayed h)
    float* __restrict__ h_hist,        // [T][B][H]
    const float* __restrict__ c0,      // [H]
    const float* __restrict__ W_ih,    // [4H, D]
    const float* __restrict__ W_hh,    // [4H, H]
    const float* __restrict__ b_ih, const float* __restrict__ b_hh,
    const float* __restrict__ tp,      // [B,T]
    const float* __restrict__ w_t, const float* __restrict__ h_t,
    int* __restrict__ bar) {
  __shared__ float Ws[32 * WS_STRIDE];      // 96.5 KB: 32 cols x 768 K, col-major
  __shared__ float As[2][64 * AS_STRIDE];   // 34 KB: double-buffered A chunks
  int tid = threadIdx.x;
  int bt = blockIdx.x & 3;        // batch group
  int ht = blockIdx.x >> 2;       // h tile
  int b0 = bt * 64, h0b = ht * 8;
  int tx = tid & 15, ty = tid >> 4;

  // --- stage weights once (32 cols = 4 gates x 8 h-units; col-major over K=768)
  for (int idx = tid; idx < 32 * 192; idx += 256) {
    int col = idx / 192;
    int s = idx - col * 192;
    int kg = s * 4;
    int g = col >> 3, hu = col & 7;
    int jw = g * Hn + h0b + hu;
    float4 v;
    if (kg < Dn) v = *(const float4*)(W_ih + (size_t)jw * Dn + kg);
    else         v = *(const float4*)(W_hh + (size_t)jw * Hn + (kg - Dn));
    *(float4*)(&Ws[col * WS_STRIDE + kg]) = v;
  }

  // --- per-thread hoists
  float bias[2];
#pragma unroll
  for (int j = 0; j < 2; ++j) {
    int col = tx + 16 * j;
    int g = col >> 3, hu = col & 7;
    int jw = g * Hn + h0b + hu;
    bias[j] = b_ih[jw] + b_hh[jw];
  }
  int hcell = h0b + (tid & 7);   // h unit this thread's 2 cells use
  float wtv = w_t[hcell], htv = h_t[hcell];
  float creg[2];
  creg[0] = creg[1] = c0[hcell];
  int brow[2];
  brow[0] = b0 + (tid >> 3);
  brow[1] = b0 + 32 + (tid >> 3);
  int* mybar = bar + bt * 128;
  __syncthreads();

  int srow = tid >> 2;             // staging row [0,64)
  int sc0 = (tid & 3) * 4;         // staging f4 slot base
  float4 pre[4];

  for (int t = 0; t < Tn; ++t) {
    const float* hdec_cur = hdec + (size_t)(t & 1) * Bn * Hn;
    float acc[4][2] = {};

    // stage chunk 0 (xs only, no barrier dep)
#pragma unroll
    for (int q = 0; q < 4; ++q) {
      int kg = (sc0 + q) * 4;
      pre[q] = *(const float4*)(xs + ((size_t)t * Bn + (b0 + srow)) * Dn + kg);
    }
#pragma unroll
    for (int q = 0; q < 4; ++q)
      *(float4*)(&As[0][srow * AS_STRIDE + (sc0 + q) * 4]) = pre[q];
    __syncthreads();

    for (int kc = 0; kc < 12; ++kc) {
      if (kc < 11) {  // preload next chunk into regs
        int kgb = (kc + 1) * 64;
#pragma unroll
        for (int q = 0; q < 4; ++q) {
          int kg = kgb + (sc0 + q) * 4;
          if (kg < Dn)
            pre[q] = *(const float4*)(xs + ((size_t)t * Bn + (b0 + srow)) * Dn + kg);
          else
            pre[q] = *(const float4*)(hdec_cur + (size_t)(b0 + srow) * Hn + (kg - Dn));
        }
      }
      const float* as = As[kc & 1];
      int kb = kc * 64;
#pragma unroll 8
      for (int kk = 0; kk < 64; kk += 4) {
        float4 av[4], bv[2];
#pragma unroll
        for (int i = 0; i < 4; ++i)
          av[i] = *(const float4*)(&as[(4 * ty + i) * AS_STRIDE + kk]);
#pragma unroll
        for (int j = 0; j < 2; ++j)
          bv[j] = *(const float4*)(&Ws[(tx + 16 * j) * WS_STRIDE + kb + kk]);
#pragma unroll
        for (int i = 0; i < 4; ++i)
#pragma unroll
          for (int j = 0; j < 2; ++j) {
            acc[i][j] += av[i].x * bv[j].x;
            acc[i][j] += av[i].y * bv[j].y;
            acc[i][j] += av[i].z * bv[j].z;
            acc[i][j] += av[i].w * bv[j].w;
          }
      }
      if (kc < 11) {  // commit preloaded chunk to other buffer
        float* ad = As[(kc + 1) & 1];
#pragma unroll
        for (int q = 0; q < 4; ++q)
          *(float4*)(&ad[srow * AS_STRIDE + (sc0 + q) * 4]) = pre[q];
      }
      __syncthreads();
    }

    // --- epilogue: gates -> LDS -> LSTM cell (2 cells/thread)
    float* Gs = (float*)As[0];
#pragma unroll
    for (int i = 0; i < 4; ++i)
#pragma unroll
      for (int j = 0; j < 2; ++j)
        Gs[(4 * ty + i) * GS_STRIDE + (tx + 16 * j)] = acc[i][j] + bias[j];
    __syncthreads();

#pragma unroll
    for (int r = 0; r < 2; ++r) {
      int b = brow[r];
      int bl = (r << 5) + (tid >> 3);
      int hu = tid & 7;
      float ipre = Gs[bl * GS_STRIDE + hu];
      float fpre = Gs[bl * GS_STRIDE + 8 + hu];
      float gpre = Gs[bl * GS_STRIDE + 16 + hu];
      float opre = Gs[bl * GS_STRIDE + 24 + hu];
      float gam = gammaH[((size_t)b * Tn + t) * Hn + hcell];
      float c1 = sigm(fpre) * (creg[r] * gam) + sigm(ipre) * tanhf(gpre);
      float gtv = sigm(tp[(size_t)b * Tn + t] * wtv + htv);
      float h1 = gtv * sigm(opre) * tanhf(c1);
      creg[r] = gtv * c1;
      h_hist[((size_t)t * Bn + b) * Hn + hcell] = h1;
      if (t + 1 < Tn) {
        float gn = gammaH[((size_t)b * Tn + (t + 1)) * Hn + hcell];
        hdec[(size_t)((t + 1) & 1) * Bn * Hn + (size_t)b * Hn + hcell] = h1 * gn;
      }
    }
    __syncthreads();  // also drains the hdec global writes before the barrier

    if (t + 1 < Tn) {
      if (tid == 0) {
        __hip_atomic_fetch_add(mybar, 1, __ATOMIC_RELEASE, __HIP_MEMORY_SCOPE_AGENT);
        int target = 64 * (t + 1);
        int spins = 0;
        while (__hip_atomic_load(mybar, __ATOMIC_ACQUIRE,
                                 __HIP_MEMORY_SCOPE_AGENT) < target) {
          __builtin_amdgcn_s_sleep(2);
          if (++spins > 20000000) break;  // bail visibly rather than hang
        }
      }
      __syncthreads();
      __threadfence();
    }
  }
}

// Batched output head; h1 read from h_hist[t]
__global__ __launch_bounds__(256) void k_head(const float* __restrict__ h_hist,
                                              const float* __restrict__ W1,
                                              const float* __restrict__ b1,
                                              const float* __restrict__ W2,
                                              const float* __restrict__ b2,
                                              float* __restrict__ outs) {
  __shared__ float sW1[Hn * 10];
  for (int i = threadIdx.x; i < Hn * 10; i += 256) sW1[i] = W1[i];
  __syncthreads();
  int idx = blockIdx.x * 256 + threadIdx.x;  // idx = tt*Bn + b
  const float4* row = (const float4*)(h_hist + (size_t)idx * Hn);
  float z1[10];
#pragma unroll
  for (int k = 0; k < 10; ++k) z1[k] = b1[k];
  for (int hq = 0; hq < Hn / 4; ++hq) {
    float4 hv = row[hq];
    float hvv[4] = {hv.x, hv.y, hv.z, hv.w};
    int hb = hq * 4;
#pragma unroll
    for (int c = 0; c < 4; ++c)
#pragma unroll
      for (int k = 0; k < 10; ++k) z1[k] += hvv[c] * sW1[(hb + c) * 10 + k];
  }
#pragma unroll
  for (int k = 0; k < 10; ++k) z1[k] = sigm(z1[k]);
  float z2[2];
#pragma unroll
  for (int c = 0; c < 2; ++c) {
    float v = b2[c];
#pragma unroll
    for (int k = 0; k < 10; ++k) v += z1[k] * W2[k * 2 + c];
    z2[c] = sigm(v);
  }
  float mx = fmaxf(z2[0], z2[1]);
  float e0 = expf(z2[0] - mx), e1 = expf(z2[1] - mx);
  float s = e0 + e1;
  outs[(size_t)idx * 2 + 0] = e0 / s;
  outs[(size_t)idx * 2 + 1] = e1 / s;
}

}  // namespace

extern "C" void kernel_launch(void* const* d_in, const int* in_sizes, int n_in,
                              void* d_out, int out_size, void* d_ws,
                              size_t ws_size, hipStream_t stream) {
  (void)in_sizes; (void)n_in; (void)out_size; (void)ws_size;
  const float* x     = (const float*)d_in[0];
  const float* dt    = (const float*)d_in[1];
  const float* mask  = (const float*)d_in[2];
  const float* tp    = (const float*)d_in[3];
  const float* xmean = (const float*)d_in[4];
  const float* h0    = (const float*)d_in[5];
  const float* c0    = (const float*)d_in[6];
  const float* w_gx  = (const float*)d_in[7];
  const float* h_gx  = (const float*)d_in[8];
  const float* w_gh  = (const float*)d_in[9];
  const float* h_gh  = (const float*)d_in[10];
  const float* w_t   = (const float*)d_in[11];
  const float* h_t   = (const float*)d_in[12];
  const float* W_ih  = (const float*)d_in[13];
  const float* W_hh  = (const float*)d_in[14];
  const float* b_ih  = (const float*)d_in[15];
  const float* b_hh  = (const float*)d_in[16];
  const float* oW1   = (const float*)d_in[17];
  const float* ob1   = (const float*)d_in[18];
  const float* oW2   = (const float*)d_in[19];
  const float* ob2   = (const float*)d_in[20];

  float* out  = (float*)d_out;
  float* outs = out;                        // [T,B,2]
  float* xhat = out + (size_t)Tn * Bn * 2;  // [T,B,D] (= xs; reused as GEMM input)

  float* ws     = (float*)d_ws;
  float* gammaH = ws;                                   // BT*H
  float* h_hist = gammaH + (size_t)BT * Hn;             // T*B*H
  float* hdec   = h_hist + (size_t)Tn * Bn * Hn;        // 2*B*H
  int*   bar    = (int*)(hdec + 2 * (size_t)Bn * Hn);   // 4 counters, 512B apart

  k_gamma_h<<<dim3(Hn / 64, BT / 64), 256, 0, stream>>>(dt, w_gh, h_gh, gammaH);
  k_xs<<<dim3(Dn / 64, BT / 64), 256, 0, stream>>>(dt, w_gx, h_gx, x, mask,
                                                   xmean, xhat);
  k_init<<<(Bn * Hn) / 256, 256, 0, stream>>>(h0, gammaH, hdec, bar);
  k_scan<<<256, 256, 0, stream>>>(xhat, gammaH, hdec, h_hist, c0, W_ih, W_hh,
                                  b_ih, b_hh, tp, w_t, h_t, bar);
  k_head<<<BT / 256, 256, 0, stream>>>(h_hist, oW1, ob1, oW2, ob2, outs);
}

// Round 3
// 4265.270 us; speedup vs baseline: 2.0961x; 1.7457x over previous
//
#include <hip/hip_runtime.h>
#include <hip/hip_bf16.h>
#include <math.h>

namespace {

constexpr int Bn = 256;
constexpr int Tn = 128;
constexpr int Dn = 256;
constexpr int Hn = 512;
constexpr int BT = Bn * Tn;

constexpr int AP = 776;  // LDS row stride in bf16 elems (768+8): dword stride 388 = 4 mod 32
constexpr int GS = 36;   // gate staging stride (floats)

typedef short bf8_t __attribute__((ext_vector_type(8)));
typedef float f32x4 __attribute__((ext_vector_type(4)));

__device__ __forceinline__ float sigm(float v) { return 1.0f / (1.0f + expf(-v)); }

__device__ __forceinline__ unsigned short f2bf(float f) {
  union { __hip_bfloat16 h; unsigned short u; } v;
  v.h = __float2bfloat16(f);
  return v.u;
}
__device__ __forceinline__ float bf2f(unsigned short u) {
  union { unsigned int i; float f; } v;
  v.i = ((unsigned int)u) << 16;
  return v.f;
}

// gamma_h[t][b][n] = exp(-relu(dt[m,:]@w_gh[:,n] + h_gh[n]))  (m = b*Tn + t)
__global__ __launch_bounds__(256) void k_gamma_h(const float* __restrict__ dt,
                                                 const float* __restrict__ w,
                                                 const float* __restrict__ bias,
                                                 float* __restrict__ outg) {
  __shared__ float As[64][17];
  __shared__ float Bs[16][64];
  int tid = threadIdx.x;
  int tx = tid & 15, ty = tid >> 4;
  int m0 = blockIdx.y * 64, n0 = blockIdx.x * 64;
  float acc[4][4] = {};
  for (int k0 = 0; k0 < Dn; k0 += 16) {
    {
      int ml = tid >> 2, kk = (tid & 3) * 4;
      float4 v = *(const float4*)(dt + (size_t)(m0 + ml) * Dn + k0 + kk);
      As[ml][kk + 0] = v.x; As[ml][kk + 1] = v.y;
      As[ml][kk + 2] = v.z; As[ml][kk + 3] = v.w;
    }
    {
      int kb = (tid >> 6) * 4, nl = tid & 63;
#pragma unroll
      for (int r = 0; r < 4; ++r)
        Bs[kb + r][nl] = w[(size_t)(k0 + kb + r) * Hn + n0 + nl];
    }
    __syncthreads();
#pragma unroll
    for (int kk = 0; kk < 16; ++kk) {
      float a[4], b[4];
#pragma unroll
      for (int i = 0; i < 4; ++i) a[i] = As[ty + 16 * i][kk];
#pragma unroll
      for (int j = 0; j < 4; ++j) b[j] = Bs[kk][tx + 16 * j];
#pragma unroll
      for (int i = 0; i < 4; ++i)
#pragma unroll
        for (int j = 0; j < 4; ++j) acc[i][j] += a[i] * b[j];
    }
    __syncthreads();
  }
#pragma unroll
  for (int j = 0; j < 4; ++j) {
    int n = n0 + tx + 16 * j;
    float bv = bias[n];
#pragma unroll
    for (int i = 0; i < 4; ++i) {
      int m = m0 + ty + 16 * i;
      int b = m >> 7, tt = m & (Tn - 1);
      float v = acc[i][j] + bv;
      outg[((size_t)tt * Bn + b) * Hn + n] = expf(-fmaxf(v, 0.0f));
    }
  }
}

// gamma_x GEMM fused with imputation; writes xs fp32 to xhats [T,B,D] and bf16 copy
__global__ __launch_bounds__(256) void k_xs(const float* __restrict__ dt,
                                            const float* __restrict__ w,
                                            const float* __restrict__ bias,
                                            const float* __restrict__ x,
                                            const float* __restrict__ mask,
                                            const float* __restrict__ xmean,
                                            float* __restrict__ out_xs,
                                            unsigned short* __restrict__ out_bf) {
  __shared__ float As[64][17];
  __shared__ float Bs[16][64];
  int tid = threadIdx.x;
  int tx = tid & 15, ty = tid >> 4;
  int m0 = blockIdx.y * 64, n0 = blockIdx.x * 64;
  float acc[4][4] = {};
  for (int k0 = 0; k0 < Dn; k0 += 16) {
    {
      int ml = tid >> 2, kk = (tid & 3) * 4;
      float4 v = *(const float4*)(dt + (size_t)(m0 + ml) * Dn + k0 + kk);
      As[ml][kk + 0] = v.x; As[ml][kk + 1] = v.y;
      As[ml][kk + 2] = v.z; As[ml][kk + 3] = v.w;
    }
    {
      int kb = (tid >> 6) * 4, nl = tid & 63;
#pragma unroll
      for (int r = 0; r < 4; ++r)
        Bs[kb + r][nl] = w[(size_t)(k0 + kb + r) * Dn + n0 + nl];
    }
    __syncthreads();
#pragma unroll
    for (int kk = 0; kk < 16; ++kk) {
      float a[4], b[4];
#pragma unroll
      for (int i = 0; i < 4; ++i) a[i] = As[ty + 16 * i][kk];
#pragma unroll
      for (int j = 0; j < 4; ++j) b[j] = Bs[kk][tx + 16 * j];
#pragma unroll
      for (int i = 0; i < 4; ++i)
#pragma unroll
        for (int j = 0; j < 4; ++j) acc[i][j] += a[i] * b[j];
    }
    __syncthreads();
  }
#pragma unroll
  for (int j = 0; j < 4; ++j) {
    int d = n0 + tx + 16 * j;
    float bv = bias[d];
    float xm = xmean[d];
#pragma unroll
    for (int i = 0; i < 4; ++i) {
      int m = m0 + ty + 16 * i;
      int b = m >> 7, tt = m & (Tn - 1);
      float g = expf(-fmaxf(acc[i][j] + bv, 0.0f));
      float imput = (tt == 0) ? xm
                              : g * x[(size_t)(m - 1) * Dn + d] + (1.0f - g) * xm;
      float xv = x[(size_t)m * Dn + d];
      float mv = mask[(size_t)m * Dn + d];
      float xsv = xv * mv + (1.0f - mv) * imput;
      size_t oi = ((size_t)tt * Bn + b) * Dn + d;
      out_xs[oi] = xsv;
      out_bf[oi] = f2bf(xsv);
    }
  }
}

// hdec_bf[0][b][h] = bf16(h0[h] * gammaT[0][b][h]); zero barrier counters
__global__ __launch_bounds__(256) void k_init(const float* __restrict__ h0,
                                              const float* __restrict__ gammaT,
                                              unsigned short* __restrict__ hdec,
                                              int* __restrict__ bar) {
  int i = blockIdx.x * 256 + threadIdx.x;  // [0, Bn*Hn) = [0][b][h]
  int h = i & (Hn - 1);
  hdec[i] = f2bf(h0[h] * gammaT[i]);
  if (blockIdx.x == 0 && threadIdx.x < 4) bar[threadIdx.x * 128] = 0;
}

// Persistent MFMA scan: 256 blocks (1/CU), 4 waves. Block owns 64 b x (8 h x 4 gates).
// bf16 weights resident in LDS; A (xs||gamma*h) staged bf16 per step; c in regs.
__global__ __launch_bounds__(256, 1) void k_scan(
    const unsigned short* __restrict__ xs_bf,  // [T,B,D] bf16
    const float* __restrict__ gammaT,          // [T,B,H] fp32
    unsigned short* __restrict__ hdec_bf,      // [2,B,H] bf16 (pre-decayed h)
    unsigned short* __restrict__ h_bf,         // [T,B,H] bf16 (h1 history)
    const float* __restrict__ c0,              // [H]
    const float* __restrict__ W_ih,            // [4H, D] fp32
    const float* __restrict__ W_hh,            // [4H, H] fp32
    const float* __restrict__ b_ih, const float* __restrict__ b_hh,
    const float* __restrict__ tp,              // [B,T]
    const float* __restrict__ w_t, const float* __restrict__ h_t,
    int* __restrict__ bar) {
  __shared__ unsigned short Wlds[32 * AP];  // 48.5 KB
  __shared__ unsigned short Alds[64 * AP];  // 97 KB
  __shared__ float Gs[64 * GS];             // 9 KB
  int tid = threadIdx.x;
  int bt = blockIdx.x & 3;   // batch group -> XCDs {bt, bt+4} under round-robin
  int ht = blockIdx.x >> 2;  // h tile
  int b0 = bt * 64, h0b = ht * 8;

  // --- stage weights once: col c = g*8+hu, K-major bf16
  for (int idx = tid; idx < 32 * 192; idx += 256) {
    int c = idx / 192;
    int s = idx - c * 192;
    int kg = s * 4;
    int g = c >> 3, hu = c & 7;
    int jw = g * Hn + h0b + hu;
    float4 wv;
    if (kg < Dn) wv = *(const float4*)(W_ih + (size_t)jw * Dn + kg);
    else         wv = *(const float4*)(W_hh + (size_t)jw * Hn + (kg - Dn));
    unsigned int u01 = (unsigned int)f2bf(wv.x) | ((unsigned int)f2bf(wv.y) << 16);
    unsigned int u23 = (unsigned int)f2bf(wv.z) | ((unsigned int)f2bf(wv.w) << 16);
    *(unsigned int*)(&Wlds[(size_t)c * AP + kg]) = u01;
    *(unsigned int*)(&Wlds[(size_t)c * AP + kg + 2]) = u23;
  }

  // --- per-thread cell hoists (2 cells: (b0+tid/8, hu) and (+32, hu))
  int hu = tid & 7;
  int hcell = h0b + hu;
  float bias[4];
#pragma unroll
  for (int g = 0; g < 4; ++g) {
    int jw = g * Hn + hcell;
    bias[g] = b_ih[jw] + b_hh[jw];
  }
  float wtv = w_t[hcell], htv = h_t[hcell];
  float creg[2];
  creg[0] = creg[1] = c0[hcell];
  int brow[2] = {b0 + (tid >> 3), b0 + 32 + (tid >> 3)};
  int bloc[2] = {tid >> 3, 32 + (tid >> 3)};
  int* mybar = bar + bt * 128;

  // --- MFMA lane mapping
  int lane = tid & 63, wv4 = tid >> 6;
  int ln = lane & 15, qd = lane >> 4;
  const unsigned short* abase = &Alds[(size_t)(wv4 * 16 + ln) * AP + qd * 8];
  const unsigned short* bb0 = &Wlds[(size_t)ln * AP + qd * 8];
  const unsigned short* bb1 = &Wlds[(size_t)(16 + ln) * AP + qd * 8];
  __syncthreads();

  for (int t = 0; t < Tn; ++t) {
    // --- stage A: xs rows (k<256) + pre-decayed h (k>=256), bf16, coalesced
    {
      const float4* xsrc = (const float4*)(xs_bf + ((size_t)t * Bn + b0) * Dn);
#pragma unroll
      for (int i = 0; i < 8; ++i) {
        int c = tid + 256 * i;
        int row = c >> 5, off = c & 31;
        float4 v = xsrc[c];
        *(float4*)(&Alds[(size_t)row * AP + off * 8]) = v;
      }
      const float4* hsrc =
          (const float4*)(hdec_bf + (size_t)(t & 1) * Bn * Hn + (size_t)b0 * Hn);
#pragma unroll
      for (int i = 0; i < 16; ++i) {
        int c = tid + 256 * i;
        int row = c >> 6, off = c & 63;
        float4 v = hsrc[c];
        *(float4*)(&Alds[(size_t)row * AP + 256 + off * 8]) = v;
      }
    }
    __syncthreads();

    // --- MFMA: 24 k-steps x 2 n-tiles
    f32x4 acc0 = {0.f, 0.f, 0.f, 0.f};
    f32x4 acc1 = {0.f, 0.f, 0.f, 0.f};
#pragma unroll
    for (int ks = 0; ks < 24; ++ks) {
      bf8_t a = *(const bf8_t*)(abase + ks * 32);
      bf8_t b0f = *(const bf8_t*)(bb0 + ks * 32);
      bf8_t b1f = *(const bf8_t*)(bb1 + ks * 32);
      acc0 = __builtin_amdgcn_mfma_f32_16x16x32_bf16(a, b0f, acc0, 0, 0, 0);
      acc1 = __builtin_amdgcn_mfma_f32_16x16x32_bf16(a, b1f, acc1, 0, 0, 0);
    }

    // --- gates -> LDS (C layout: col=lane&15, row=quad*4+reg)
#pragma unroll
    for (int r = 0; r < 4; ++r) {
      int grow = wv4 * 16 + qd * 4 + r;
      Gs[grow * GS + ln] = acc0[r];
      Gs[grow * GS + 16 + ln] = acc1[r];
    }
    __syncthreads();

    // --- LSTM cell, 2 cells/thread
#pragma unroll
    for (int r = 0; r < 2; ++r) {
      int b = brow[r];
      int bl = bloc[r];
      float ipre = Gs[bl * GS + hu] + bias[0];
      float fpre = Gs[bl * GS + 8 + hu] + bias[1];
      float gpre = Gs[bl * GS + 16 + hu] + bias[2];
      float opre = Gs[bl * GS + 24 + hu] + bias[3];
      float gam = gammaT[((size_t)t * Bn + b) * Hn + hcell];
      float c1 = sigm(fpre) * (creg[r] * gam) + sigm(ipre) * tanhf(gpre);
      float gtv = sigm(tp[(size_t)b * Tn + t] * wtv + htv);
      float h1 = gtv * sigm(opre) * tanhf(c1);
      creg[r] = gtv * c1;
      h_bf[((size_t)t * Bn + b) * Hn + hcell] = f2bf(h1);
      if (t + 1 < Tn) {
        float gn = gammaT[((size_t)(t + 1) * Bn + b) * Hn + hcell];
        hdec_bf[(size_t)((t + 1) & 1) * Bn * Hn + (size_t)b * Hn + hcell] =
            f2bf(h1 * gn);
      }
    }
    __syncthreads();

    // --- device barrier over this batch group's 64 blocks
    if (t + 1 < Tn) {
      if (tid == 0) {
        __hip_atomic_fetch_add(mybar, 1, __ATOMIC_RELEASE, __HIP_MEMORY_SCOPE_AGENT);
        int target = 64 * (t + 1);
        int spins = 0;
        while (__hip_atomic_load(mybar, __ATOMIC_ACQUIRE,
                                 __HIP_MEMORY_SCOPE_AGENT) < target) {
          __builtin_amdgcn_s_sleep(2);
          if (++spins > 20000000) break;  // bail visibly rather than hang
        }
      }
      __syncthreads();
      __threadfence();
    }
  }
}

// Batched output head over all (t,b) rows; h1 read from bf16 history
__global__ __launch_bounds__(256) void k_head(const unsigned short* __restrict__ h_bf,
                                              const float* __restrict__ W1,
                                              const float* __restrict__ b1,
                                              const float* __restrict__ W2,
                                              const float* __restrict__ b2,
                                              float* __restrict__ outs) {
  __shared__ float sW1[Hn * 10];
  for (int i = threadIdx.x; i < Hn * 10; i += 256) sW1[i] = W1[i];
  __syncthreads();
  int idx = blockIdx.x * 256 + threadIdx.x;  // idx = tt*Bn + b
  const uint4* row = (const uint4*)(h_bf + (size_t)idx * Hn);
  float z1[10];
#pragma unroll
  for (int k = 0; k < 10; ++k) z1[k] = b1[k];
  for (int hq = 0; hq < Hn / 8; ++hq) {
    uint4 u = row[hq];
    float hv[8];
    hv[0] = bf2f(u.x & 0xffff); hv[1] = bf2f(u.x >> 16);
    hv[2] = bf2f(u.y & 0xffff); hv[3] = bf2f(u.y >> 16);
    hv[4] = bf2f(u.z & 0xffff); hv[5] = bf2f(u.z >> 16);
    hv[6] = bf2f(u.w & 0xffff); hv[7] = bf2f(u.w >> 16);
    int hb = hq * 8;
#pragma unroll
    for (int c = 0; c < 8; ++c)
#pragma unroll
      for (int k = 0; k < 10; ++k) z1[k] += hv[c] * sW1[(hb + c) * 10 + k];
  }
#pragma unroll
  for (int k = 0; k < 10; ++k) z1[k] = sigm(z1[k]);
  float z2[2];
#pragma unroll
  for (int c = 0; c < 2; ++c) {
    float v = b2[c];
#pragma unroll
    for (int k = 0; k < 10; ++k) v += z1[k] * W2[k * 2 + c];
    z2[c] = sigm(v);
  }
  float mx = fmaxf(z2[0], z2[1]);
  float e0 = expf(z2[0] - mx), e1 = expf(z2[1] - mx);
  float s = e0 + e1;
  outs[(size_t)idx * 2 + 0] = e0 / s;
  outs[(size_t)idx * 2 + 1] = e1 / s;
}

}  // namespace

extern "C" void kernel_launch(void* const* d_in, const int* in_sizes, int n_in,
                              void* d_out, int out_size, void* d_ws,
                              size_t ws_size, hipStream_t stream) {
  (void)in_sizes; (void)n_in; (void)out_size; (void)ws_size;
  const float* x     = (const float*)d_in[0];
  const float* dt    = (const float*)d_in[1];
  const float* mask  = (const float*)d_in[2];
  const float* tp    = (const float*)d_in[3];
  const float* xmean = (const float*)d_in[4];
  const float* h0    = (const float*)d_in[5];
  const float* c0    = (const float*)d_in[6];
  const float* w_gx  = (const float*)d_in[7];
  const float* h_gx  = (const float*)d_in[8];
  const float* w_gh  = (const float*)d_in[9];
  const float* h_gh  = (const float*)d_in[10];
  const float* w_t   = (const float*)d_in[11];
  const float* h_t   = (const float*)d_in[12];
  const float* W_ih  = (const float*)d_in[13];
  const float* W_hh  = (const float*)d_in[14];
  const float* b_ih  = (const float*)d_in[15];
  const float* b_hh  = (const float*)d_in[16];
  const float* oW1   = (const float*)d_in[17];
  const float* ob1   = (const float*)d_in[18];
  const float* oW2   = (const float*)d_in[19];
  const float* ob2   = (const float*)d_in[20];

  float* out  = (float*)d_out;
  float* outs = out;                        // [T,B,2]
  float* xhat = out + (size_t)Tn * Bn * 2;  // [T,B,D] fp32 (output 1)

  float* ws = (float*)d_ws;
  float* gammaT = ws;  // [T,B,H] fp32: 67.1 MB
  unsigned short* xs_bf   = (unsigned short*)(gammaT + (size_t)BT * Hn);  // 16.8 MB
  unsigned short* h_bf    = xs_bf + (size_t)BT * Dn;                      // 33.6 MB
  unsigned short* hdec_bf = h_bf + (size_t)BT * Hn;                       // 0.5 MB
  int* bar = (int*)(hdec_bf + 2 * (size_t)Bn * Hn);

  k_gamma_h<<<dim3(Hn / 64, BT / 64), 256, 0, stream>>>(dt, w_gh, h_gh, gammaT);
  k_xs<<<dim3(Dn / 64, BT / 64), 256, 0, stream>>>(dt, w_gx, h_gx, x, mask,
                                                   xmean, xhat, xs_bf);
  k_init<<<(Bn * Hn) / 256, 256, 0, stream>>>(h0, gammaT, hdec_bf, bar);
  k_scan<<<256, 256, 0, stream>>>(xs_bf, gammaT, hdec_bf, h_bf, c0, W_ih, W_hh,
                                  b_ih, b_hh, tp, w_t, h_t, bar);
  k_head<<<BT / 256, 256, 0, stream>>>(h_bf, oW1, ob1, oW2, ob2, outs);
}